// Round 9
// baseline (27156.912 us; speedup 1.0000x reference)
//
#include <hip/hip_runtime.h>
#include <math.h>

#define N_BUS 2000
#define N_EDGE 6000
#define N2 4000
#define NB 64
#define NPANELS 35
#define MPAD (NB * NPANELS) /* 2240 */
#define LD 2308
#define DCOL 2244 /* G = D^{-1} tiles stored at cols [DCOL, DCOL+64) */
#define T_STEPS 5
#define EPSR 1e-6f
#define NBLK 1024
#define SPIN_CAP 50000000
#define NSUB 64
#define SUBSTRIDE 16 /* 64B padding between sub-counters */

__global__ __launch_bounds__(1024) void prep_once_kernel(
    const float* __restrict__ x, const int* __restrict__ bus_type,
    const float* __restrict__ br_r, const float* __restrict__ br_x,
    float* va, float* vm, float* gsa, float* bsa, int* kmap, int* m_dev) {
  __shared__ int cnt[1024];
  const int tid = threadIdx.x;
  int kept[4];
  int c = 0;
#pragma unroll
  for (int k = 0; k < 4; ++k) {
    int j = tid * 4 + k;
    kept[k] = 0;
    if (j < N2) {
      bool kp = (j < N_BUS) ? (bus_type[j] != 3) : (bus_type[j - N_BUS] == 1);
      kept[k] = kp ? 1 : 0;
      c += kept[k];
    }
  }
  cnt[tid] = c;
  __syncthreads();
  for (int off = 1; off < 1024; off <<= 1) {
    int v = cnt[tid];
    int u = (tid >= off) ? cnt[tid - off] : 0;
    __syncthreads();
    cnt[tid] = v + u;
    __syncthreads();
  }
  int base = cnt[tid] - c;  // exclusive prefix
#pragma unroll
  for (int k = 0; k < 4; ++k) {
    int j = tid * 4 + k;
    if (j < N2) kmap[j] = kept[k] ? base++ : -1;
  }
  if (tid == 1023) *m_dev = cnt[1023];
  for (int e = tid; e < N_EDGE; e += 1024) {
    float r = br_r[e], xx = br_x[e];
    float den = r * r + xx * xx;
    gsa[e] = r / den;
    bsa[e] = -xx / den;
  }
  for (int i = tid; i < N_BUS; i += 1024) {
    va[i] = x[i];
    vm[i] = x[N_BUS + i];
  }
}

// Fused: clear M + per-step prep (dxc, Pacc/Qacc zero, sync state zero).
__global__ void clear_prep_kernel(float4* __restrict__ M4,
                                  const int* __restrict__ bus_type,
                                  const float* __restrict__ vsp,
                                  const float* __restrict__ va,
                                  const float* __restrict__ vm, float* dxc,
                                  float* Pacc, float* Qacc, int* xflag,
                                  int* wflag, int* subcnt, int* epoch) {
  int t = blockIdx.x * blockDim.x + threadIdx.x;
  if (t < MPAD * LD / 4) M4[t] = float4{0.f, 0.f, 0.f, 0.f};
  if (t < N2) {
    if (t < N_BUS) {
      Pacc[t] = 0.f;
      Qacc[t] = 0.f;
      int bt = bus_type[t];
      dxc[t] = (bt == 3) ? va[t] / (1.f + EPSR) : 0.f;
    } else {
      int i = t - N_BUS;
      int bt = bus_type[i];
      dxc[t] = (bt >= 2) ? (vm[i] - vsp[i]) / (1.f + EPSR) : 0.f;
    }
  }
  if (t < 64) xflag[t] = 0;
  else if (t < 128) wflag[t - 64] = 0;
  else if (t < 128 + NSUB * SUBSTRIDE) subcnt[t - 128] = 0;
  else if (t == 2000) *epoch = 0;
}

__device__ __forceinline__ void addJ(float* __restrict__ M,
                                     const int* __restrict__ kmap,
                                     const float* __restrict__ dxc, int r,
                                     int C, float v) {
  int c = kmap[C];
  if (c >= 0)
    atomicAdd(&M[(size_t)r * LD + c], v);
  else
    atomicAdd(&M[(size_t)r * LD + MPAD], -v * dxc[C]);
}

__global__ void edge_kernel(const int* __restrict__ ei,
                            const float* __restrict__ gsa,
                            const float* __restrict__ bsa,
                            const float* __restrict__ g_fr,
                            const float* __restrict__ b_fr,
                            const float* __restrict__ g_to,
                            const float* __restrict__ b_to,
                            const float* __restrict__ tapA,
                            const float* __restrict__ shiftA,
                            const float* __restrict__ va,
                            const float* __restrict__ vm,
                            const int* __restrict__ kmap,
                            const float* __restrict__ dxc,
                            float* __restrict__ M, float* __restrict__ Pacc,
                            float* __restrict__ Qacc) {
  int e = blockIdx.x * blockDim.x + threadIdx.x;
  if (e >= N_EDGE) return;
  int s = ei[e], d = ei[N_EDGE + e];
  float g = gsa[e], b = bsa[e];
  float ti = 1.f / tapA[e];
  float vi = vm[s], vj = vm[d];
  float th = (va[s] - va[d]) - shiftA[e];
  float cf = cosf(th), sf = sinf(th);
  float vij = vi * vj * ti;
  float Af = g * cf + b * sf, Bf = g * sf - b * cf;
  float At = g * cf - b * sf, Bt = -g * sf - b * cf;
  float vit = vi * ti;
  float Pf = vit * vit * (g + g_fr[e]) + vij * (-g * cf - b * sf);
  float Qf = -vit * vit * (b + b_fr[e]) + vij * (-g * sf + b * cf);
  float Pt = vj * vj * (g + g_to[e]) + vij * (-g * cf + b * sf);
  float Qt = -vj * vj * (b + b_to[e]) + vij * (g * sf + b * cf);
  atomicAdd(&Pacc[s], Pf);
  atomicAdd(&Qacc[s], Qf);
  atomicAdd(&Pacc[d], Pt);
  atomicAdd(&Qacc[d], Qt);
  int rPs = kmap[s], rPd = kmap[d];
  int rQs = kmap[N_BUS + s], rQd = kmap[N_BUS + d];
  if (rPs >= 0) {
    addJ(M, kmap, dxc, rPs, s, -vij * Bf);
    addJ(M, kmap, dxc, rPs, d, vij * Bf);
    addJ(M, kmap, dxc, rPs, N_BUS + s,
         -2.f * vi * ti * ti * (g + g_fr[e]) + vj * ti * Af);
    addJ(M, kmap, dxc, rPs, N_BUS + d, vi * ti * Af);
  }
  if (rQs >= 0) {
    addJ(M, kmap, dxc, rQs, s, vij * Af);
    addJ(M, kmap, dxc, rQs, d, -vij * Af);
    addJ(M, kmap, dxc, rQs, N_BUS + s,
         2.f * vi * ti * ti * (b + b_fr[e]) + vj * ti * Bf);
    addJ(M, kmap, dxc, rQs, N_BUS + d, vi * ti * Bf);
  }
  if (rPd >= 0) {
    addJ(M, kmap, dxc, rPd, d, -vij * Bt);
    addJ(M, kmap, dxc, rPd, s, vij * Bt);
    addJ(M, kmap, dxc, rPd, N_BUS + d,
         -2.f * vj * (g + g_to[e]) + vi * ti * At);
    addJ(M, kmap, dxc, rPd, N_BUS + s, vj * ti * At);
  }
  if (rQd >= 0) {
    addJ(M, kmap, dxc, rQd, d, vij * At);
    addJ(M, kmap, dxc, rQd, s, -vij * At);
    addJ(M, kmap, dxc, rQd, N_BUS + d,
         2.f * vj * (b + b_to[e]) + vi * ti * Bt);
    addJ(M, kmap, dxc, rQd, N_BUS + s, vj * ti * Bt);
  }
}

__global__ void finalize_kernel(const float* __restrict__ p_spec,
                                const float* __restrict__ q_spec,
                                const float* __restrict__ gsN,
                                const float* __restrict__ bsN,
                                const float* __restrict__ va,
                                const float* __restrict__ vm,
                                const int* __restrict__ kmap,
                                const float* __restrict__ dxc,
                                const int* __restrict__ m_dev,
                                float* __restrict__ M,
                                const float* __restrict__ Pacc,
                                const float* __restrict__ Qacc) {
  int t = blockIdx.x * blockDim.x + threadIdx.x;
  if (t < N_BUS) {
    int r = kmap[t];
    if (r >= 0) {
      float* row = &M[(size_t)r * LD];
      row[r] += EPSR;
      int cq = kmap[N_BUS + t];
      float val = -2.f * vm[t] * gsN[t];
      if (cq >= 0)
        row[cq] += val;
      else
        row[MPAD] -= val * dxc[N_BUS + t];
      float Pc = Pacc[t] + vm[t] * vm[t] * gsN[t];
      row[MPAD] += p_spec[t] - Pc;
    }
  } else if (t < N2) {
    int i = t - N_BUS;
    int r = kmap[t];
    if (r >= 0) {
      float* row = &M[(size_t)r * LD];
      row[r] += 2.f * vm[i] * bsN[i] + EPSR;
      float Qc = Qacc[i] - vm[i] * vm[i] * bsN[i];
      row[MPAD] += q_spec[i] - Qc;
    }
  } else if (t < N2 + MPAD) {
    int r = t - N2;
    if (r >= *m_dev) M[(size_t)r * LD + r] = 1.f;
  }
}

// ---------------- persistent solve kernel ----------------

__device__ __forceinline__ int aload(const int* p) {
  return __hip_atomic_load(p, __ATOMIC_RELAXED, __HIP_MEMORY_SCOPE_AGENT);
}
__device__ __forceinline__ float aloadf(const float* p) {
  return __hip_atomic_load(p, __ATOMIC_RELAXED, __HIP_MEMORY_SCOPE_AGENT);
}
__device__ __forceinline__ void astoref(float* p, float v) {
  __hip_atomic_store(p, v, __ATOMIC_RELAXED, __HIP_MEMORY_SCOPE_AGENT);
}

// Master/worker epoch barrier (block 0 aggregates; workers poll one line).
__device__ __forceinline__ void gbar(int* subcnt, int* epoch, int bk) {
  __syncthreads();
  if (threadIdx.x == 0) {
    __threadfence();  // release (L2 kept clean by atomic M stores -> cheap)
    __hip_atomic_fetch_add(&subcnt[(blockIdx.x & (NSUB - 1)) * SUBSTRIDE], 1,
                           __ATOMIC_RELEASE, __HIP_MEMORY_SCOPE_AGENT);
    if (blockIdx.x == 0) {
      int it = 0;
      while (it < SPIN_CAP) {
        int s = 0;
#pragma unroll
        for (int i = 0; i < NSUB; ++i) s += aload(&subcnt[i * SUBSTRIDE]);
        if (s >= NBLK * bk) break;
        __builtin_amdgcn_s_sleep(1);
        ++it;
      }
      __hip_atomic_store(epoch, bk, __ATOMIC_RELEASE,
                         __HIP_MEMORY_SCOPE_AGENT);
    } else {
      int it = 0;
      while (aload(epoch) < bk && it < SPIN_CAP) {
        __builtin_amdgcn_s_sleep(8);
        ++it;
      }
    }
    __threadfence();  // acquire (invalidate clean lines -> cheap)
  }
  __syncthreads();
}

template <int SLP>
__device__ __forceinline__ void wait_val(const int* f, int v) {
  if (threadIdx.x == 0) {
    int it = 0;
    while (aload(f) < v && it < SPIN_CAP) {
      __builtin_amdgcn_s_sleep(SLP);
      ++it;
    }
  }
  __syncthreads();
}

// acc = A(64x64) * B(64x64), this thread's 4x4 at (trow, tcol).
__device__ __forceinline__ void gemm64(const float (*A)[68],
                                       const float (*B)[68], int tid,
                                       float acc[4][4]) {
  const int trow = (tid >> 4) * 4;
  const int tcol = (tid & 15) * 4;
#pragma unroll
  for (int ii = 0; ii < 4; ++ii)
#pragma unroll
    for (int jj = 0; jj < 4; ++jj) acc[ii][jj] = 0.f;
#pragma unroll
  for (int k4 = 0; k4 < 16; ++k4) {
    float ar[4][4], br[4][4];
#pragma unroll
    for (int ii = 0; ii < 4; ++ii) {
      float4 tv = *(const float4*)&A[trow + ii][k4 * 4];
      ar[ii][0] = tv.x; ar[ii][1] = tv.y; ar[ii][2] = tv.z; ar[ii][3] = tv.w;
    }
#pragma unroll
    for (int kk = 0; kk < 4; ++kk) {
      float4 tv = *(const float4*)&B[k4 * 4 + kk][tcol];
      br[kk][0] = tv.x; br[kk][1] = tv.y; br[kk][2] = tv.z; br[kk][3] = tv.w;
    }
#pragma unroll
    for (int kk = 0; kk < 4; ++kk)
#pragma unroll
      for (int ii = 0; ii < 4; ++ii)
#pragma unroll
        for (int jj = 0; jj < 4; ++jj)
          acc[ii][jj] = fmaf(ar[ii][kk], br[kk][jj], acc[ii][jj]);
  }
}

// In-place Gauss-Jordan inverse of 64x64 tile in LDS (stride 68), no pivot.
__device__ __forceinline__ void gj_invert64(float (*A)[68],
                                            float* __restrict__ colk,
                                            int tid) {
  const int c = tid & 63, q = tid >> 6;
#pragma unroll 1
  for (int k = 0; k < 64; ++k) {
    if (tid < 64) colk[tid] = A[tid][k];
    float rkc = A[k][c];
    __syncthreads();
    float d = 1.f / colk[k];
    float ukc = rkc * d;
#pragma unroll
    for (int i4 = 0; i4 < 16; ++i4) {
      int i = q + i4 * 4;
      if (i == k) {
        A[k][c] = (c == k) ? d : ukc;
      } else {
        float e = colk[i];
        A[i][c] = (c == k) ? (-e * d) : fmaf(-e, ukc, A[i][c]);
      }
    }
    __syncthreads();
  }
}

// W(j) = G * A12(j), overwrite in place; leaves W in Ws; publishes wflag.
__device__ __forceinline__ void produce_W(float* __restrict__ M, int s0, int j,
                                          int p, float (*As)[68],
                                          float (*Ws)[68], int* wflag,
                                          int tid) {
  const int c0 = s0 + j * 64;
  for (int idx = tid; idx < 1024; idx += 256) {
    int rr = idx >> 4, q4 = (idx & 15) * 4;
    *(float4*)&As[rr][q4] =
        *(const float4*)&M[(size_t)(s0 + rr) * LD + DCOL + q4];
    *(float4*)&Ws[rr][q4] = *(const float4*)&M[(size_t)(s0 + rr) * LD + c0 + q4];
  }
  __syncthreads();
  float acc[4][4];
  gemm64(As, Ws, tid, acc);
  __syncthreads();
  const int trow = (tid >> 4) * 4, tcol = (tid & 15) * 4;
#pragma unroll
  for (int ii = 0; ii < 4; ++ii) {
#pragma unroll
    for (int jj = 0; jj < 4; ++jj) {
      Ws[trow + ii][tcol + jj] = acc[ii][jj];
      astoref(&M[(size_t)(s0 + trow + ii) * LD + c0 + tcol + jj], acc[ii][jj]);
    }
  }
  __syncthreads();
  if (tid == 0)
    __hip_atomic_store(&wflag[p + j], p + 1, __ATOMIC_RELEASE,
                       __HIP_MEMORY_SCOPE_AGENT);
}

// C(i,j) -= A21(i) * W(j)   (W read coherently; C written coherently)
__device__ __forceinline__ void consume_C(float* __restrict__ M, int s0, int i,
                                          int j, float (*As)[68],
                                          float (*Ws)[68], int tid) {
  const int r0 = s0 + i * 64, c0 = s0 + j * 64;
  const int trow = (tid >> 4) * 4, tcol = (tid & 15) * 4;
  for (int idx = tid; idx < 4096; idx += 256)
    Ws[idx >> 6][idx & 63] =
        aloadf(&M[(size_t)(s0 + (idx >> 6)) * LD + c0 + (idx & 63)]);
  for (int idx = tid; idx < 1024; idx += 256) {
    int rr = idx >> 4, q4 = (idx & 15) * 4;
    *(float4*)&As[rr][q4] = *(const float4*)&M[(size_t)(r0 + rr) * LD + s0 + q4];
  }
  float4 cold[4];
#pragma unroll
  for (int ii = 0; ii < 4; ++ii)
    cold[ii] = *(const float4*)&M[(size_t)(r0 + trow + ii) * LD + c0 + tcol];
  __syncthreads();
  float acc[4][4];
  gemm64(As, Ws, tid, acc);
#pragma unroll
  for (int ii = 0; ii < 4; ++ii) {
    float* crow = &M[(size_t)(r0 + trow + ii) * LD + c0 + tcol];
    astoref(&crow[0], ((const float*)&cold[ii])[0] - acc[ii][0]);
    astoref(&crow[1], ((const float*)&cold[ii])[1] - acc[ii][1]);
    astoref(&crow[2], ((const float*)&cold[ii])[2] - acc[ii][2]);
    astoref(&crow[3], ((const float*)&cold[ii])[3] - acc[ii][3]);
  }
}

__global__ __launch_bounds__(256, 4) void solve_kernel(
    float* __restrict__ M, float* __restrict__ dxv, int* __restrict__ xflag,
    int* __restrict__ wflag, int* __restrict__ subcnt, int* __restrict__ epoch,
    const int* __restrict__ kmap, const float* __restrict__ dxc, float* va,
    float* vm, float* __restrict__ out) {
  __shared__ __align__(16) float As[64][68];
  __shared__ __align__(16) float Ws[64][68];
  __shared__ float colk[64];
  __shared__ float zbuf[64];
  const int tid = threadIdx.x, blk = blockIdx.x;
  int bk = 0;

  // Prologue: block 0 inverts D0.
  if (blk == 0) {
    for (int idx = tid; idx < 1024; idx += 256) {
      int rr = idx >> 4, q4 = (idx & 15) * 4;
      *(float4*)&Ws[rr][q4] = *(const float4*)&M[(size_t)rr * LD + q4];
    }
    __syncthreads();
    gj_invert64(Ws, colk, tid);
    for (int idx = tid; idx < 4096; idx += 256)
      astoref(&M[(size_t)(idx >> 6) * LD + DCOL + (idx & 63)],
              Ws[idx >> 6][idx & 63]);
  }
  ++bk;
  gbar(subcnt, epoch, bk);

  // Forward elimination
  for (int p = 0; p < NPANELS - 1; ++p) {
    const int ntr = NPANELS - 1 - p;
    const int s0 = p * NB;
    const int nunits = ntr * ntr + ntr;
    if (blk == 0) {
      // W(1) -> C(1,1) -> invert next diag
      produce_W(M, s0, 1, p, As, Ws, wflag, tid);  // Ws holds W(1)
      const int r0 = s0 + 64, c0 = s0 + 64;
      const int trow = (tid >> 4) * 4, tcol = (tid & 15) * 4;
      for (int idx = tid; idx < 1024; idx += 256) {
        int rr = idx >> 4, q4 = (idx & 15) * 4;
        *(float4*)&As[rr][q4] =
            *(const float4*)&M[(size_t)(r0 + rr) * LD + s0 + q4];
      }
      float4 cold[4];
#pragma unroll
      for (int ii = 0; ii < 4; ++ii)
        cold[ii] =
            *(const float4*)&M[(size_t)(r0 + trow + ii) * LD + c0 + tcol];
      __syncthreads();
      float acc[4][4];
      gemm64(As, Ws, tid, acc);
      float cn[4][4];
#pragma unroll
      for (int ii = 0; ii < 4; ++ii) {
        cn[ii][0] = ((const float*)&cold[ii])[0] - acc[ii][0];
        cn[ii][1] = ((const float*)&cold[ii])[1] - acc[ii][1];
        cn[ii][2] = ((const float*)&cold[ii])[2] - acc[ii][2];
        cn[ii][3] = ((const float*)&cold[ii])[3] - acc[ii][3];
        float* crow = &M[(size_t)(r0 + trow + ii) * LD + c0 + tcol];
        astoref(&crow[0], cn[ii][0]);
        astoref(&crow[1], cn[ii][1]);
        astoref(&crow[2], cn[ii][2]);
        astoref(&crow[3], cn[ii][3]);
      }
      __syncthreads();  // all Ws reads done
#pragma unroll
      for (int ii = 0; ii < 4; ++ii) {
        Ws[trow + ii][tcol + 0] = cn[ii][0];
        Ws[trow + ii][tcol + 1] = cn[ii][1];
        Ws[trow + ii][tcol + 2] = cn[ii][2];
        Ws[trow + ii][tcol + 3] = cn[ii][3];
      }
      __syncthreads();
      gj_invert64(Ws, colk, tid);
      for (int idx = tid; idx < 4096; idx += 256)
        astoref(&M[(size_t)(s0 + 64 + (idx >> 6)) * LD + DCOL + (idx & 63)],
                Ws[idx >> 6][idx & 63]);
    } else {
      if (blk < ntr) {
        produce_W(M, s0, blk + 1, p, As, Ws, wflag, tid);
      } else if (blk == ntr) {
        // z = G * f_p (overwrite f_p)
        for (int idx = tid; idx < 1024; idx += 256) {
          int rr = idx >> 4, q4 = (idx & 15) * 4;
          *(float4*)&As[rr][q4] =
              *(const float4*)&M[(size_t)(s0 + rr) * LD + DCOL + q4];
        }
        if (tid < 64) colk[tid] = M[(size_t)(s0 + tid) * LD + MPAD];
        __syncthreads();
        const int r = tid >> 2, c4 = tid & 3, kb = c4 * 16;
        float z = 0.f;
#pragma unroll
        for (int k4 = 0; k4 < 4; ++k4) {
          float4 g = *(const float4*)&As[r][kb + k4 * 4];
          z = fmaf(g.x, colk[kb + k4 * 4 + 0], z);
          z = fmaf(g.y, colk[kb + k4 * 4 + 1], z);
          z = fmaf(g.z, colk[kb + k4 * 4 + 2], z);
          z = fmaf(g.w, colk[kb + k4 * 4 + 3], z);
        }
        z += __shfl_down(z, 2, 4);
        z += __shfl_down(z, 1, 4);
        if (c4 == 0) zbuf[r] = z;
        __syncthreads();
        if (tid < 64) astoref(&M[(size_t)(s0 + tid) * LD + MPAD], zbuf[tid]);
        __syncthreads();
        if (tid == 0)
          __hip_atomic_store(&wflag[NPANELS], p + 1, __ATOMIC_RELEASE,
                             __HIP_MEMORY_SCOPE_AGENT);
      }
      // consumer loop (all worker blocks, incl. producers when done)
      for (int u = blk; u < nunits; u += NBLK - 1) {
        if (u < ntr * ntr) {
          int i = u / ntr + 1, j = u % ntr + 1;
          wait_val<2>(&wflag[p + j], p + 1);
          consume_C(M, s0, i, j, As, Ws, tid);
        } else {
          int i = u - ntr * ntr + 1;
          wait_val<2>(&wflag[NPANELS], p + 1);
          if (tid < 64) zbuf[tid] = aloadf(&M[(size_t)(s0 + tid) * LD + MPAD]);
          __syncthreads();
          const int r = tid >> 2, c4 = tid & 3, kb = c4 * 16;
          const int rg = s0 + i * 64 + r;
          float a = 0.f;
#pragma unroll
          for (int k4 = 0; k4 < 4; ++k4) {
            float4 av = *(const float4*)&M[(size_t)rg * LD + s0 + kb + k4 * 4];
            a = fmaf(av.x, zbuf[kb + k4 * 4 + 0], a);
            a = fmaf(av.y, zbuf[kb + k4 * 4 + 1], a);
            a = fmaf(av.z, zbuf[kb + k4 * 4 + 2], a);
            a = fmaf(av.w, zbuf[kb + k4 * 4 + 3], a);
          }
          a += __shfl_down(a, 2, 4);
          a += __shfl_down(a, 1, 4);
          if (c4 == 0) {
            float fo = M[(size_t)rg * LD + MPAD];
            astoref(&M[(size_t)rg * LD + MPAD], fo - a);
          }
          __syncthreads();
        }
      }
    }
    ++bk;
    gbar(subcnt, epoch, bk);
  }

  // Backward substitution: flag chain. For jb < NPANELS-1: x = z - sum W x.
  if (blk < NPANELS) {
    const int jb = blk, b0 = jb * NB;
    const int r = tid >> 2, c4 = tid & 3, kb = c4 * 16;
    if (jb == NPANELS - 1) {
      for (int idx = tid; idx < 1024; idx += 256) {
        int rr = idx >> 4, q4 = (idx & 15) * 4;
        *(float4*)&As[rr][q4] =
            *(const float4*)&M[(size_t)(b0 + rr) * LD + DCOL + q4];
      }
      if (tid < 64) colk[tid] = M[(size_t)(b0 + tid) * LD + MPAD];
      __syncthreads();
      float z = 0.f;
#pragma unroll
      for (int k4 = 0; k4 < 4; ++k4) {
        float4 g = *(const float4*)&As[r][kb + k4 * 4];
        z = fmaf(g.x, colk[kb + k4 * 4 + 0], z);
        z = fmaf(g.y, colk[kb + k4 * 4 + 1], z);
        z = fmaf(g.z, colk[kb + k4 * 4 + 2], z);
        z = fmaf(g.w, colk[kb + k4 * 4 + 3], z);
      }
      z += __shfl_down(z, 2, 4);
      z += __shfl_down(z, 1, 4);
      if (c4 == 0) zbuf[r] = z;
      __syncthreads();
      if (tid < 64) astoref(&dxv[b0 + tid], zbuf[tid]);
    } else {
      float fr = (c4 == 0) ? M[(size_t)(b0 + r) * LD + MPAD] : 0.f;
      float acc = 0.f;
      for (int q = NPANELS - 1; q > jb; --q) {
        const float* trow = &M[(size_t)(b0 + r) * LD + q * 64 + kb];
        float4 t0 = *(const float4*)&trow[0];
        float4 t1 = *(const float4*)&trow[4];
        float4 t2 = *(const float4*)&trow[8];
        float4 t3 = *(const float4*)&trow[12];
        wait_val<2>(&xflag[q], 1);
        const float* xq = &dxv[q * 64 + kb];
        acc = fmaf(t0.x, aloadf(&xq[0]), acc);
        acc = fmaf(t0.y, aloadf(&xq[1]), acc);
        acc = fmaf(t0.z, aloadf(&xq[2]), acc);
        acc = fmaf(t0.w, aloadf(&xq[3]), acc);
        acc = fmaf(t1.x, aloadf(&xq[4]), acc);
        acc = fmaf(t1.y, aloadf(&xq[5]), acc);
        acc = fmaf(t1.z, aloadf(&xq[6]), acc);
        acc = fmaf(t1.w, aloadf(&xq[7]), acc);
        acc = fmaf(t2.x, aloadf(&xq[8]), acc);
        acc = fmaf(t2.y, aloadf(&xq[9]), acc);
        acc = fmaf(t2.z, aloadf(&xq[10]), acc);
        acc = fmaf(t2.w, aloadf(&xq[11]), acc);
        acc = fmaf(t3.x, aloadf(&xq[12]), acc);
        acc = fmaf(t3.y, aloadf(&xq[13]), acc);
        acc = fmaf(t3.z, aloadf(&xq[14]), acc);
        acc = fmaf(t3.w, aloadf(&xq[15]), acc);
      }
      acc += __shfl_down(acc, 2, 4);
      acc += __shfl_down(acc, 1, 4);
      if (c4 == 0) colk[r] = fr - acc;
      __syncthreads();
      if (tid < 64) astoref(&dxv[b0 + tid], colk[tid]);
    }
    __syncthreads();
    if (tid == 0)
      __hip_atomic_store(&xflag[jb], 1, __ATOMIC_RELEASE,
                         __HIP_MEMORY_SCOPE_AGENT);
  }

  // Final fused state update + output
  wait_val<16>(&xflag[0], 1);
  for (int t = blk * 256 + tid; t < N2; t += NBLK * 256) {
    int rr = kmap[t];
    float d = (rr >= 0) ? aloadf(&dxv[rr]) : dxc[t];
    if (t < N_BUS) {
      float v = va[t] - d;
      va[t] = v;
      out[t] = v;
    } else {
      int i2 = t - N_BUS;
      float v = vm[i2] - d;
      v = fminf(fmaxf(v, 0.5f), 1.5f);
      vm[i2] = v;
      out[t] = v;
    }
  }
}

extern "C" void kernel_launch(void* const* d_in, const int* in_sizes, int n_in,
                              void* d_out, int out_size, void* d_ws,
                              size_t ws_size, hipStream_t stream) {
  const float* x = (const float*)d_in[0];
  const int* ei = (const int*)d_in[1];
  const float* br_r = (const float*)d_in[2];
  const float* br_x = (const float*)d_in[3];
  const float* g_fr = (const float*)d_in[4];
  const float* b_fr = (const float*)d_in[5];
  const float* g_to = (const float*)d_in[6];
  const float* b_to = (const float*)d_in[7];
  const float* tap = (const float*)d_in[8];
  const float* shift = (const float*)d_in[9];
  const float* p_spec = (const float*)d_in[10];
  const float* q_spec = (const float*)d_in[11];
  const float* gsN = (const float*)d_in[12];
  const float* bsN = (const float*)d_in[13];
  const int* bus_type = (const int*)d_in[14];
  const float* vsp = (const float*)d_in[15];
  float* out = (float*)d_out;

  float* W = (float*)d_ws;
  float* M = W;
  float* dxc = W + (size_t)MPAD * LD;
  float* va = dxc + N2;
  float* vm = va + N_BUS;
  float* Pacc = vm + N_BUS;
  float* Qacc = Pacc + N_BUS;
  float* gsa = Qacc + N_BUS;
  float* bsa = gsa + N_EDGE;
  int* kmap = (int*)(bsa + N_EDGE);
  int* m_dev = kmap + N2;
  int* xflag = m_dev + 1;                  // 64 ints
  int* wflag = xflag + 64;                 // 64 ints (zflag = wflag[NPANELS])
  int* subcnt = wflag + 64;                // NSUB*SUBSTRIDE ints
  int* epoch = subcnt + NSUB * SUBSTRIDE;  // 16 ints
  float* dxv = (float*)(epoch + 16);

  prep_once_kernel<<<1, 1024, 0, stream>>>(x, bus_type, br_r, br_x, va, vm,
                                           gsa, bsa, kmap, m_dev);
  const int clear_blocks = (MPAD * LD / 4 + 255) / 256;
  for (int t = 0; t < T_STEPS; ++t) {
    clear_prep_kernel<<<clear_blocks, 256, 0, stream>>>(
        (float4*)M, bus_type, vsp, va, vm, dxc, Pacc, Qacc, xflag, wflag,
        subcnt, epoch);
    edge_kernel<<<(N_EDGE + 255) / 256, 256, 0, stream>>>(
        ei, gsa, bsa, g_fr, b_fr, g_to, b_to, tap, shift, va, vm, kmap, dxc, M,
        Pacc, Qacc);
    finalize_kernel<<<(N2 + MPAD + 255) / 256, 256, 0, stream>>>(
        p_spec, q_spec, gsN, bsN, va, vm, kmap, dxc, m_dev, M, Pacc, Qacc);
    solve_kernel<<<NBLK, 256, 0, stream>>>(M, dxv, xflag, wflag, subcnt, epoch,
                                           kmap, dxc, va, vm, out);
  }
}

// Round 10
// 18495.255 us; speedup vs baseline: 1.4683x; 1.4683x over previous
//
#include <hip/hip_runtime.h>
#include <math.h>

#define N_BUS 2000
#define N_EDGE 6000
#define N2 4000
#define NB 64
#define NPANELS 35
#define MPAD (NB * NPANELS) /* 2240 */
#define LD 2308
#define DCOL 2244 /* G = D^{-1} tiles stored at cols [DCOL, DCOL+64) */
#define T_STEPS 5
#define EPSR 1e-6f
#define PBLK 512 /* blocks per panel launch: 511 tile-blocks + 1 RHS block */
#define SPIN_CAP 50000000

__global__ __launch_bounds__(1024) void prep_once_kernel(
    const float* __restrict__ x, const int* __restrict__ bus_type,
    const float* __restrict__ br_r, const float* __restrict__ br_x,
    float* va, float* vm, float* gsa, float* bsa, int* kmap, int* m_dev) {
  __shared__ int cnt[1024];
  const int tid = threadIdx.x;
  int kept[4];
  int c = 0;
#pragma unroll
  for (int k = 0; k < 4; ++k) {
    int j = tid * 4 + k;
    kept[k] = 0;
    if (j < N2) {
      bool kp = (j < N_BUS) ? (bus_type[j] != 3) : (bus_type[j - N_BUS] == 1);
      kept[k] = kp ? 1 : 0;
      c += kept[k];
    }
  }
  cnt[tid] = c;
  __syncthreads();
  for (int off = 1; off < 1024; off <<= 1) {
    int v = cnt[tid];
    int u = (tid >= off) ? cnt[tid - off] : 0;
    __syncthreads();
    cnt[tid] = v + u;
    __syncthreads();
  }
  int base = cnt[tid] - c;  // exclusive prefix
#pragma unroll
  for (int k = 0; k < 4; ++k) {
    int j = tid * 4 + k;
    if (j < N2) kmap[j] = kept[k] ? base++ : -1;
  }
  if (tid == 1023) *m_dev = cnt[1023];
  for (int e = tid; e < N_EDGE; e += 1024) {
    float r = br_r[e], xx = br_x[e];
    float den = r * r + xx * xx;
    gsa[e] = r / den;
    bsa[e] = -xx / den;
  }
  for (int i = tid; i < N_BUS; i += 1024) {
    va[i] = x[i];
    vm[i] = x[N_BUS + i];
  }
}

// Fused: clear M + per-step prep (dxc, Pacc/Qacc zero, backsub flags zero).
__global__ void clear_prep_kernel(float4* __restrict__ M4,
                                  const int* __restrict__ bus_type,
                                  const float* __restrict__ vsp,
                                  const float* __restrict__ va,
                                  const float* __restrict__ vm, float* dxc,
                                  float* Pacc, float* Qacc, int* xflag) {
  int t = blockIdx.x * blockDim.x + threadIdx.x;
  if (t < MPAD * LD / 4) M4[t] = float4{0.f, 0.f, 0.f, 0.f};
  if (t < N2) {
    if (t < N_BUS) {
      Pacc[t] = 0.f;
      Qacc[t] = 0.f;
      int bt = bus_type[t];
      dxc[t] = (bt == 3) ? va[t] / (1.f + EPSR) : 0.f;
    } else {
      int i = t - N_BUS;
      int bt = bus_type[i];
      dxc[t] = (bt >= 2) ? (vm[i] - vsp[i]) / (1.f + EPSR) : 0.f;
    }
  }
  if (t < 64) xflag[t] = 0;
}

__device__ __forceinline__ void addJ(float* __restrict__ M,
                                     const int* __restrict__ kmap,
                                     const float* __restrict__ dxc, int r,
                                     int C, float v) {
  int c = kmap[C];
  if (c >= 0)
    atomicAdd(&M[(size_t)r * LD + c], v);
  else
    atomicAdd(&M[(size_t)r * LD + MPAD], -v * dxc[C]);
}

__global__ void edge_kernel(const int* __restrict__ ei,
                            const float* __restrict__ gsa,
                            const float* __restrict__ bsa,
                            const float* __restrict__ g_fr,
                            const float* __restrict__ b_fr,
                            const float* __restrict__ g_to,
                            const float* __restrict__ b_to,
                            const float* __restrict__ tapA,
                            const float* __restrict__ shiftA,
                            const float* __restrict__ va,
                            const float* __restrict__ vm,
                            const int* __restrict__ kmap,
                            const float* __restrict__ dxc,
                            float* __restrict__ M, float* __restrict__ Pacc,
                            float* __restrict__ Qacc) {
  int e = blockIdx.x * blockDim.x + threadIdx.x;
  if (e >= N_EDGE) return;
  int s = ei[e], d = ei[N_EDGE + e];
  float g = gsa[e], b = bsa[e];
  float ti = 1.f / tapA[e];
  float vi = vm[s], vj = vm[d];
  float th = (va[s] - va[d]) - shiftA[e];
  float cf = cosf(th), sf = sinf(th);
  float vij = vi * vj * ti;
  float Af = g * cf + b * sf, Bf = g * sf - b * cf;
  float At = g * cf - b * sf, Bt = -g * sf - b * cf;
  float vit = vi * ti;
  float Pf = vit * vit * (g + g_fr[e]) + vij * (-g * cf - b * sf);
  float Qf = -vit * vit * (b + b_fr[e]) + vij * (-g * sf + b * cf);
  float Pt = vj * vj * (g + g_to[e]) + vij * (-g * cf + b * sf);
  float Qt = -vj * vj * (b + b_to[e]) + vij * (g * sf + b * cf);
  atomicAdd(&Pacc[s], Pf);
  atomicAdd(&Qacc[s], Qf);
  atomicAdd(&Pacc[d], Pt);
  atomicAdd(&Qacc[d], Qt);
  int rPs = kmap[s], rPd = kmap[d];
  int rQs = kmap[N_BUS + s], rQd = kmap[N_BUS + d];
  if (rPs >= 0) {
    addJ(M, kmap, dxc, rPs, s, -vij * Bf);
    addJ(M, kmap, dxc, rPs, d, vij * Bf);
    addJ(M, kmap, dxc, rPs, N_BUS + s,
         -2.f * vi * ti * ti * (g + g_fr[e]) + vj * ti * Af);
    addJ(M, kmap, dxc, rPs, N_BUS + d, vi * ti * Af);
  }
  if (rQs >= 0) {
    addJ(M, kmap, dxc, rQs, s, vij * Af);
    addJ(M, kmap, dxc, rQs, d, -vij * Af);
    addJ(M, kmap, dxc, rQs, N_BUS + s,
         2.f * vi * ti * ti * (b + b_fr[e]) + vj * ti * Bf);
    addJ(M, kmap, dxc, rQs, N_BUS + d, vi * ti * Bf);
  }
  if (rPd >= 0) {
    addJ(M, kmap, dxc, rPd, d, -vij * Bt);
    addJ(M, kmap, dxc, rPd, s, vij * Bt);
    addJ(M, kmap, dxc, rPd, N_BUS + d,
         -2.f * vj * (g + g_to[e]) + vi * ti * At);
    addJ(M, kmap, dxc, rPd, N_BUS + s, vj * ti * At);
  }
  if (rQd >= 0) {
    addJ(M, kmap, dxc, rQd, d, vij * At);
    addJ(M, kmap, dxc, rQd, s, -vij * At);
    addJ(M, kmap, dxc, rQd, N_BUS + d,
         2.f * vj * (b + b_to[e]) + vi * ti * Bt);
    addJ(M, kmap, dxc, rQd, N_BUS + s, vj * ti * Bt);
  }
}

__global__ void finalize_kernel(const float* __restrict__ p_spec,
                                const float* __restrict__ q_spec,
                                const float* __restrict__ gsN,
                                const float* __restrict__ bsN,
                                const float* __restrict__ va,
                                const float* __restrict__ vm,
                                const int* __restrict__ kmap,
                                const float* __restrict__ dxc,
                                const int* __restrict__ m_dev,
                                float* __restrict__ M,
                                const float* __restrict__ Pacc,
                                const float* __restrict__ Qacc) {
  int t = blockIdx.x * blockDim.x + threadIdx.x;
  if (t < N_BUS) {
    int r = kmap[t];
    if (r >= 0) {
      float* row = &M[(size_t)r * LD];
      row[r] += EPSR;
      int cq = kmap[N_BUS + t];
      float val = -2.f * vm[t] * gsN[t];
      if (cq >= 0)
        row[cq] += val;
      else
        row[MPAD] -= val * dxc[N_BUS + t];
      float Pc = Pacc[t] + vm[t] * vm[t] * gsN[t];
      row[MPAD] += p_spec[t] - Pc;
    }
  } else if (t < N2) {
    int i = t - N_BUS;
    int r = kmap[t];
    if (r >= 0) {
      float* row = &M[(size_t)r * LD];
      row[r] += 2.f * vm[i] * bsN[i] + EPSR;
      float Qc = Qacc[i] - vm[i] * vm[i] * bsN[i];
      row[MPAD] += q_spec[i] - Qc;
    }
  } else if (t < N2 + MPAD) {
    int r = t - N2;
    if (r >= *m_dev) M[(size_t)r * LD + r] = 1.f;
  }
}

// acc = A(64x64) * B(64x64), this thread's 4x4 at (trow, tcol).
__device__ __forceinline__ void gemm64(const float (*A)[68],
                                       const float (*B)[68], int tid,
                                       float acc[4][4]) {
  const int trow = (tid >> 4) * 4;
  const int tcol = (tid & 15) * 4;
#pragma unroll
  for (int ii = 0; ii < 4; ++ii)
#pragma unroll
    for (int jj = 0; jj < 4; ++jj) acc[ii][jj] = 0.f;
#pragma unroll
  for (int k4 = 0; k4 < 16; ++k4) {
    float ar[4][4], br[4][4];
#pragma unroll
    for (int ii = 0; ii < 4; ++ii) {
      float4 tv = *(const float4*)&A[trow + ii][k4 * 4];
      ar[ii][0] = tv.x; ar[ii][1] = tv.y; ar[ii][2] = tv.z; ar[ii][3] = tv.w;
    }
#pragma unroll
    for (int kk = 0; kk < 4; ++kk) {
      float4 tv = *(const float4*)&B[k4 * 4 + kk][tcol];
      br[kk][0] = tv.x; br[kk][1] = tv.y; br[kk][2] = tv.z; br[kk][3] = tv.w;
    }
#pragma unroll
    for (int kk = 0; kk < 4; ++kk)
#pragma unroll
      for (int ii = 0; ii < 4; ++ii)
#pragma unroll
        for (int jj = 0; jj < 4; ++jj)
          acc[ii][jj] = fmaf(ar[ii][kk], br[kk][jj], acc[ii][jj]);
  }
}

// In-place Gauss-Jordan inverse of 64x64 tile in LDS (stride 68), no pivot.
__device__ __forceinline__ void gj_invert64(float (*A)[68],
                                            float* __restrict__ colk,
                                            int tid) {
  const int c = tid & 63, q = tid >> 6;
#pragma unroll 1
  for (int k = 0; k < 64; ++k) {
    if (tid < 64) colk[tid] = A[tid][k];
    float rkc = A[k][c];
    __syncthreads();
    float d = 1.f / colk[k];
    float ukc = rkc * d;
#pragma unroll
    for (int i4 = 0; i4 < 16; ++i4) {
      int i = q + i4 * 4;
      if (i == k) {
        A[k][c] = (c == k) ? d : ukc;
      } else {
        float e = colk[i];
        A[i][c] = (c == k) ? (-e * d) : fmaf(-e, ukc, A[i][c]);
      }
    }
    __syncthreads();
  }
}

__global__ __launch_bounds__(256) void invert0_kernel(float* __restrict__ M) {
  __shared__ __align__(16) float A[64][68];
  __shared__ float colk[64];
  const int tid = threadIdx.x;
  for (int idx = tid; idx < 1024; idx += 256) {
    int rr = idx >> 4, q4 = (idx & 15) * 4;
    *(float4*)&A[rr][q4] = *(const float4*)&M[(size_t)rr * LD + q4];
  }
  __syncthreads();
  gj_invert64(A, colk, tid);
  for (int idx = tid; idx < 4096; idx += 256)
    M[(size_t)(idx >> 6) * LD + DCOL + (idx & 63)] = A[idx >> 6][idx & 63];
}

// One launch per panel p. Fully independent blocks (no intra-launch comms):
//  block PBLK-1      : RHS  f_i -= A21(i) * (G * f_p), i = 1..ntr
//  blocks 0..PBLK-2  : column j = 1 + blk%ntr, chunk ch = blk/ntr (< nch);
//                      W(j) = G*A12(j) once in LDS, then C(i,j) -= A21(i)*W(j)
//                      for i = 1+ch, 1+ch+nch, ...
//  block 0 (i==1,j==1): also Gauss-Jordan-inverts the fresh C(1,1) -> G_{p+1}
__global__ __launch_bounds__(256) void panel_kernel(float* __restrict__ M,
                                                    int p) {
  const int ntr = NPANELS - 1 - p;
  const int s0 = p * NB;
  const int tid = threadIdx.x, blk = blockIdx.x;
  __shared__ __align__(16) float Gs[64][68];
  __shared__ __align__(16) float Ws[64][68];
  __shared__ __align__(16) float As[64][68];
  __shared__ float colk[64];
  __shared__ float zb[64];

  if (blk == PBLK - 1) {
    // ---- RHS block ----
    for (int idx = tid; idx < 1024; idx += 256) {
      int rr = idx >> 4, q4 = (idx & 15) * 4;
      *(float4*)&Gs[rr][q4] =
          *(const float4*)&M[(size_t)(s0 + rr) * LD + DCOL + q4];
    }
    if (tid < 64) colk[tid] = M[(size_t)(s0 + tid) * LD + MPAD];
    __syncthreads();
    const int r = tid >> 2, c4 = tid & 3, kb = c4 * 16;
    float z = 0.f;
#pragma unroll
    for (int k4 = 0; k4 < 4; ++k4) {
      float4 g = *(const float4*)&Gs[r][kb + k4 * 4];
      z = fmaf(g.x, colk[kb + k4 * 4 + 0], z);
      z = fmaf(g.y, colk[kb + k4 * 4 + 1], z);
      z = fmaf(g.z, colk[kb + k4 * 4 + 2], z);
      z = fmaf(g.w, colk[kb + k4 * 4 + 3], z);
    }
    z += __shfl_down(z, 2, 4);
    z += __shfl_down(z, 1, 4);
    if (c4 == 0) zb[r] = z;
    __syncthreads();
    for (int i = 1; i <= ntr; ++i) {
      const int rg = s0 + i * 64 + r;
      float a = 0.f;
#pragma unroll
      for (int k4 = 0; k4 < 4; ++k4) {
        float4 av = *(const float4*)&M[(size_t)rg * LD + s0 + kb + k4 * 4];
        a = fmaf(av.x, zb[kb + k4 * 4 + 0], a);
        a = fmaf(av.y, zb[kb + k4 * 4 + 1], a);
        a = fmaf(av.z, zb[kb + k4 * 4 + 2], a);
        a = fmaf(av.w, zb[kb + k4 * 4 + 3], a);
      }
      a += __shfl_down(a, 2, 4);
      a += __shfl_down(a, 1, 4);
      if (c4 == 0) M[(size_t)rg * LD + MPAD] -= a;
    }
    return;
  }

  // ---- tile blocks ----
  const int nch = (PBLK - 1) / ntr;
  const int ch = blk / ntr;
  if (ch >= nch) return;  // avoid duplicate i-coverage (race-free)
  const int j = 1 + blk % ntr;
  const int c0 = s0 + j * 64;
  for (int idx = tid; idx < 1024; idx += 256) {
    int rr = idx >> 4, q4 = (idx & 15) * 4;
    *(float4*)&Gs[rr][q4] =
        *(const float4*)&M[(size_t)(s0 + rr) * LD + DCOL + q4];
    *(float4*)&As[rr][q4] =
        *(const float4*)&M[(size_t)(s0 + rr) * LD + c0 + q4];
  }
  __syncthreads();
  const int trow = (tid >> 4) * 4, tcol = (tid & 15) * 4;
  float acc[4][4];
  gemm64(Gs, As, tid, acc);  // W(j) = G * A12(j)
  __syncthreads();
#pragma unroll
  for (int ii = 0; ii < 4; ++ii) {
    float4 tv{acc[ii][0], acc[ii][1], acc[ii][2], acc[ii][3]};
    *(float4*)&Ws[trow + ii][tcol] = tv;
  }
  __syncthreads();

  for (int i = 1 + ch; i <= ntr; i += nch) {
    const int r0 = s0 + i * 64;
    for (int idx = tid; idx < 1024; idx += 256) {
      int rr = idx >> 4, q4 = (idx & 15) * 4;
      *(float4*)&As[rr][q4] =
          *(const float4*)&M[(size_t)(r0 + rr) * LD + s0 + q4];
    }
    float4 cold[4];
#pragma unroll
    for (int ii = 0; ii < 4; ++ii)
      cold[ii] = *(const float4*)&M[(size_t)(r0 + trow + ii) * LD + c0 + tcol];
    __syncthreads();
    gemm64(As, Ws, tid, acc);  // A21(i) * W(j)
    float cn[4][4];
#pragma unroll
    for (int ii = 0; ii < 4; ++ii) {
      cn[ii][0] = ((const float*)&cold[ii])[0] - acc[ii][0];
      cn[ii][1] = ((const float*)&cold[ii])[1] - acc[ii][1];
      cn[ii][2] = ((const float*)&cold[ii])[2] - acc[ii][2];
      cn[ii][3] = ((const float*)&cold[ii])[3] - acc[ii][3];
      float4 tv{cn[ii][0], cn[ii][1], cn[ii][2], cn[ii][3]};
      *(float4*)&M[(size_t)(r0 + trow + ii) * LD + c0 + tcol] = tv;
    }
    if (blk == 0 && i == 1) {
      // invert fresh C(1,1) -> G_{p+1}
      __syncthreads();  // all As/Ws reads of this gemm done
#pragma unroll
      for (int ii = 0; ii < 4; ++ii) {
        As[trow + ii][tcol + 0] = cn[ii][0];
        As[trow + ii][tcol + 1] = cn[ii][1];
        As[trow + ii][tcol + 2] = cn[ii][2];
        As[trow + ii][tcol + 3] = cn[ii][3];
      }
      __syncthreads();
      gj_invert64(As, colk, tid);
      for (int idx = tid; idx < 4096; idx += 256)
        M[(size_t)(s0 + 64 + (idx >> 6)) * LD + DCOL + (idx & 63)] =
            As[idx >> 6][idx & 63];
    }
    __syncthreads();  // protect As/Ws before next i overwrites As
  }
}

__device__ __forceinline__ int aload(const int* p) {
  return __hip_atomic_load(p, __ATOMIC_RELAXED, __HIP_MEMORY_SCOPE_AGENT);
}

template <int SLP>
__device__ __forceinline__ void wait_flag(const int* f) {
  if (threadIdx.x == 0) {
    int it = 0;
    while (aload(f) == 0 && it < SPIN_CAP) {
      __builtin_amdgcn_s_sleep(SLP);
      ++it;
    }
    __threadfence();
  }
  __syncthreads();
}

// Backward substitution: 35 co-resident blocks, flag chain; fused update.
__global__ __launch_bounds__(256) void backsub_kernel(
    const float* __restrict__ M, float* __restrict__ dxv,
    int* __restrict__ xflag, const int* __restrict__ kmap,
    const float* __restrict__ dxc, float* va, float* vm,
    float* __restrict__ out) {
  __shared__ __align__(16) float Gs[64][68];
  __shared__ float colk[64];
  __shared__ float zb[64];
  const int tid = threadIdx.x, jb = blockIdx.x;
  const int b0 = jb * NB;
  const int r = tid >> 2, c4 = tid & 3, kb = c4 * 16;
  for (int idx = tid; idx < 1024; idx += 256) {
    int rr = idx >> 4, q4 = (idx & 15) * 4;
    *(float4*)&Gs[rr][q4] =
        *(const float4*)&M[(size_t)(b0 + rr) * LD + DCOL + q4];
  }
  __syncthreads();
  float fr = (c4 == 0) ? M[(size_t)(b0 + r) * LD + MPAD] : 0.f;
  float acc = 0.f;
  for (int q = NPANELS - 1; q > jb; --q) {
    const float* trow = &M[(size_t)(b0 + r) * LD + q * 64 + kb];
    float4 t0 = *(const float4*)&trow[0];
    float4 t1 = *(const float4*)&trow[4];
    float4 t2 = *(const float4*)&trow[8];
    float4 t3 = *(const float4*)&trow[12];
    wait_flag<2>(&xflag[q]);
    const float* xq = &dxv[q * 64 + kb];
    acc = fmaf(t0.x, xq[0], acc);
    acc = fmaf(t0.y, xq[1], acc);
    acc = fmaf(t0.z, xq[2], acc);
    acc = fmaf(t0.w, xq[3], acc);
    acc = fmaf(t1.x, xq[4], acc);
    acc = fmaf(t1.y, xq[5], acc);
    acc = fmaf(t1.z, xq[6], acc);
    acc = fmaf(t1.w, xq[7], acc);
    acc = fmaf(t2.x, xq[8], acc);
    acc = fmaf(t2.y, xq[9], acc);
    acc = fmaf(t2.z, xq[10], acc);
    acc = fmaf(t2.w, xq[11], acc);
    acc = fmaf(t3.x, xq[12], acc);
    acc = fmaf(t3.y, xq[13], acc);
    acc = fmaf(t3.z, xq[14], acc);
    acc = fmaf(t3.w, xq[15], acc);
  }
  acc += __shfl_down(acc, 2, 4);
  acc += __shfl_down(acc, 1, 4);
  if (c4 == 0) colk[r] = fr - acc;
  __syncthreads();
  float z = 0.f;
#pragma unroll
  for (int k4 = 0; k4 < 4; ++k4) {
    float4 g = *(const float4*)&Gs[r][kb + k4 * 4];
    z = fmaf(g.x, colk[kb + k4 * 4 + 0], z);
    z = fmaf(g.y, colk[kb + k4 * 4 + 1], z);
    z = fmaf(g.z, colk[kb + k4 * 4 + 2], z);
    z = fmaf(g.w, colk[kb + k4 * 4 + 3], z);
  }
  z += __shfl_down(z, 2, 4);
  z += __shfl_down(z, 1, 4);
  if (c4 == 0) zb[r] = z;
  __syncthreads();
  if (tid < 64) dxv[b0 + tid] = zb[tid];
  __syncthreads();
  if (tid == 0) {
    __threadfence();
    atomicExch(&xflag[jb], 1);
  }
  // fused state update + output
  wait_flag<16>(&xflag[0]);
  for (int t = jb * 256 + tid; t < N2; t += NPANELS * 256) {
    int rr = kmap[t];
    float d = (rr >= 0) ? dxv[rr] : dxc[t];
    if (t < N_BUS) {
      float v = va[t] - d;
      va[t] = v;
      out[t] = v;
    } else {
      int i2 = t - N_BUS;
      float v = vm[i2] - d;
      v = fminf(fmaxf(v, 0.5f), 1.5f);
      vm[i2] = v;
      out[t] = v;
    }
  }
}

extern "C" void kernel_launch(void* const* d_in, const int* in_sizes, int n_in,
                              void* d_out, int out_size, void* d_ws,
                              size_t ws_size, hipStream_t stream) {
  const float* x = (const float*)d_in[0];
  const int* ei = (const int*)d_in[1];
  const float* br_r = (const float*)d_in[2];
  const float* br_x = (const float*)d_in[3];
  const float* g_fr = (const float*)d_in[4];
  const float* b_fr = (const float*)d_in[5];
  const float* g_to = (const float*)d_in[6];
  const float* b_to = (const float*)d_in[7];
  const float* tap = (const float*)d_in[8];
  const float* shift = (const float*)d_in[9];
  const float* p_spec = (const float*)d_in[10];
  const float* q_spec = (const float*)d_in[11];
  const float* gsN = (const float*)d_in[12];
  const float* bsN = (const float*)d_in[13];
  const int* bus_type = (const int*)d_in[14];
  const float* vsp = (const float*)d_in[15];
  float* out = (float*)d_out;

  float* W = (float*)d_ws;
  float* M = W;
  float* dxc = W + (size_t)MPAD * LD;
  float* va = dxc + N2;
  float* vm = va + N_BUS;
  float* Pacc = vm + N_BUS;
  float* Qacc = Pacc + N_BUS;
  float* gsa = Qacc + N_BUS;
  float* bsa = gsa + N_EDGE;
  int* kmap = (int*)(bsa + N_EDGE);
  int* m_dev = kmap + N2;
  int* xflag = m_dev + 1;  // 64 ints
  float* dxv = (float*)(xflag + 64);

  prep_once_kernel<<<1, 1024, 0, stream>>>(x, bus_type, br_r, br_x, va, vm,
                                           gsa, bsa, kmap, m_dev);
  const int clear_blocks = (MPAD * LD / 4 + 255) / 256;
  for (int t = 0; t < T_STEPS; ++t) {
    clear_prep_kernel<<<clear_blocks, 256, 0, stream>>>(
        (float4*)M, bus_type, vsp, va, vm, dxc, Pacc, Qacc, xflag);
    edge_kernel<<<(N_EDGE + 255) / 256, 256, 0, stream>>>(
        ei, gsa, bsa, g_fr, b_fr, g_to, b_to, tap, shift, va, vm, kmap, dxc, M,
        Pacc, Qacc);
    finalize_kernel<<<(N2 + MPAD + 255) / 256, 256, 0, stream>>>(
        p_spec, q_spec, gsN, bsN, va, vm, kmap, dxc, m_dev, M, Pacc, Qacc);
    invert0_kernel<<<1, 256, 0, stream>>>(M);
    for (int p = 0; p < NPANELS - 1; ++p)
      panel_kernel<<<PBLK, 256, 0, stream>>>(M, p);
    backsub_kernel<<<NPANELS, 256, 0, stream>>>(M, dxv, xflag, kmap, dxc, va,
                                                vm, out);
  }
}